// Round 13
// baseline (138.978 us; speedup 1.0000x reference)
//
#include <hip/hip_runtime.h>
#include <hip/hip_bf16.h>
#include <math.h>

#define N_NODES 50000
#define N_EDGES 800000
#define E_TOT   (N_EDGES + N_NODES)   // edges + self-loops
#define NEG_SLOPE 0.2f
#define SLOT_CAP 64                   // max in-degree ~45 (Poisson 17); guard only
#define N4 ((size_t)N_NODES * 4)
#define GEMM_BLOCKS ((N_NODES + 63) / 64)      // 782
#define BUCKET_BLOCKS ((E_TOT + 255) / 256)    // 3321

__device__ __forceinline__ float lrelu(float x) { return x >= 0.f ? x : NEG_SLOPE * x; }
__device__ __forceinline__ float frcp(float x) { return __builtin_amdgcn_rcpf(x); }

// slot4 packed layout: slot[(pos>>2)*N4 + node*4 + (pos&3)]
__device__ __forceinline__ size_t slot_idx(int pos, int n) {
    return (size_t)(pos >> 2) * N4 + (size_t)n * 4 + (pos & 3);
}

// round-to-nearest-even fp32 -> bf16 (as uint16 in low bits)
__device__ __forceinline__ unsigned bf16r(float x) {
    unsigned u = __float_as_uint(x);
    return (u + 0x7fffu + ((u >> 16) & 1u)) >> 16;
}
__device__ __forceinline__ unsigned pack2(float lo, float hi) {
    return bf16r(lo) | (bf16r(hi) << 16);
}
__device__ __forceinline__ float bflo(unsigned u) { return __uint_as_float(u << 16); }
__device__ __forceinline__ float bfhi(unsigned u) { return __uint_as_float(u & 0xffff0000u); }

// ========== fused: layer-1 GEMM (blocks < GEMM_BLOCKS) + edge bucketing =====
__global__ __launch_bounds__(256) void
gemm1_bucket(const float* __restrict__ x, const float* __restrict__ W1,
             const float* __restrict__ att_s, const float* __restrict__ att_d,
             unsigned* __restrict__ h1u, float* __restrict__ as1,
             float* __restrict__ ad1,
             const int* __restrict__ ei, int* __restrict__ cnt,
             int* __restrict__ slot) {
    int b = blockIdx.x;
    if (b >= GEMM_BLOCKS) {
        // ---- bucketing path ----
        int e = (b - GEMM_BLOCKS) * 256 + threadIdx.x;
        if (e < E_TOT) {
            int s, d;
            if (e < N_EDGES) { s = ei[e]; d = ei[N_EDGES + e]; }
            else             { s = d = e - N_EDGES; }
            int pos = atomicAdd(&cnt[d], 1);
            if (pos < SLOT_CAP) slot[slot_idx(pos, d)] = s;
        }
        return;
    }
    // ---- gemm path ----
    int t = threadIdx.x;
    int w = __builtin_amdgcn_readfirstlane(t >> 6);   // wave-uniform head id
    int l = t & 63;
    int nbase = b * 64;

    __shared__ float xs[64][65];      // 16.25 KB

    const float4* xv = (const float4*)(x + (size_t)nbase * 64);
    int nvalid = min(64, N_NODES - nbase);
    for (int i = t; i < nvalid * 16; i += 256) {
        float4 v = xv[i];
        int n = i >> 4, k4 = (i & 15) * 4;
        xs[n][k4] = v.x; xs[n][k4 + 1] = v.y; xs[n][k4 + 2] = v.z; xs[n][k4 + 3] = v.w;
    }
    __syncthreads();

    float acc[32];
#pragma unroll
    for (int e = 0; e < 32; ++e) acc[e] = 0.f;

#pragma unroll 4
    for (int k = 0; k < 64; ++k) {
        float xk = xs[l][k];
        const float4* wr = (const float4*)(W1 + k * 128 + w * 32);  // uniform -> s_load
#pragma unroll
        for (int e4 = 0; e4 < 8; ++e4) {
            float4 wv = wr[e4];
            acc[e4 * 4 + 0] += xk * wv.x;
            acc[e4 * 4 + 1] += xk * wv.y;
            acc[e4 * 4 + 2] += xk * wv.z;
            acc[e4 * 4 + 3] += xk * wv.w;
        }
    }

    int n = nbase + l;
    if (n < N_NODES) {
        uint4* hv = (uint4*)(h1u + (size_t)n * 64 + w * 16);
#pragma unroll
        for (int e4 = 0; e4 < 4; ++e4) {
            uint4 pk;
            pk.x = pack2(acc[e4 * 8 + 0], acc[e4 * 8 + 1]);
            pk.y = pack2(acc[e4 * 8 + 2], acc[e4 * 8 + 3]);
            pk.z = pack2(acc[e4 * 8 + 4], acc[e4 * 8 + 5]);
            pk.w = pack2(acc[e4 * 8 + 6], acc[e4 * 8 + 7]);
            hv[e4] = pk;
        }
        float ps = 0.f, pd = 0.f;
#pragma unroll
        for (int e = 0; e < 32; ++e) {
            ps += acc[e] * att_s[w * 32 + e];
            pd += acc[e] * att_d[w * 32 + e];
        }
        as1[n * 4 + w] = ps;
        ad1[n * 4 + w] = pd;
    }
}

// ============== layer 1 node agg + fused layer-2 GEMM, wave-per-node ========
__global__ void node_agg1(const int* __restrict__ cnt, const int* __restrict__ slot,
                          const float* __restrict__ as1, const float* __restrict__ ad1,
                          const uint4* __restrict__ h1q, const float* __restrict__ b1,
                          const float* __restrict__ W2, const float* __restrict__ att_s2,
                          const float* __restrict__ att_d2,
                          unsigned* __restrict__ h2u, float* __restrict__ as2,
                          float* __restrict__ ad2) {
    int tb = threadIdx.x;
    int wv = tb >> 6, t = tb & 63;
    int n = blockIdx.x * 2 + wv;          // N_NODES even: always < N_NODES
    int deg = min(cnt[n], SLOT_CAP);
    float4 ad = *(const float4*)(ad1 + n * 4);

    __shared__ float els[2][SLOT_CAP * 4];   // per-edge exp(e), 4 heads
    __shared__ int  slds[2][SLOT_CAP];
    __shared__ float hrow[2][128];

    // phase A: lane = (edge, head); packed slot (4 consecutive ints per quad)
    {
        int ah = t & 3;
        float adh = (ah == 0) ? ad.x : (ah == 1) ? ad.y : (ah == 2) ? ad.z : ad.w;
        for (int p = (t >> 2); p < deg; p += 16) {
            int s = slot[slot_idx(p, n)];          // quad-coalesced + broadcast
            els[wv][p * 4 + ah] = __expf(lrelu(as1[s * 4 + ah] + adh));
            if (ah == 0) slds[wv][p] = s;
        }
    }
    __syncthreads();

    // phase C: 4 edge-groups x 16 octs (8 dims each), dual-stream 16B gathers
    int oct = t & 15, g = t >> 4, hq = oct >> 2;
    float a0 = 0.f, a1 = 0.f, a2 = 0.f, a3 = 0.f;
    float a4 = 0.f, a5 = 0.f, a6 = 0.f, a7 = 0.f;
    float accE = 0.f;
#pragma unroll 2
    for (int p = g; p < deg; p += 8) {
        float exA = els[wv][p * 4 + hq];
        uint4 hvA = h1q[(size_t)slds[wv][p] * 16 + oct];
        int pB = p + 4;
        float exB = 0.f;
        uint4 hvB = make_uint4(0u, 0u, 0u, 0u);
        if (pB < deg) {
            exB = els[wv][pB * 4 + hq];
            hvB = h1q[(size_t)slds[wv][pB] * 16 + oct];
        }
        accE += exA + exB;
        a0 += exA * bflo(hvA.x) + exB * bflo(hvB.x);
        a1 += exA * bfhi(hvA.x) + exB * bfhi(hvB.x);
        a2 += exA * bflo(hvA.y) + exB * bflo(hvB.y);
        a3 += exA * bfhi(hvA.y) + exB * bfhi(hvB.y);
        a4 += exA * bflo(hvA.z) + exB * bflo(hvB.z);
        a5 += exA * bfhi(hvA.z) + exB * bfhi(hvB.z);
        a6 += exA * bflo(hvA.w) + exB * bflo(hvB.w);
        a7 += exA * bfhi(hvA.w) + exB * bfhi(hvB.w);
    }
    for (int m = 16; m <= 32; m <<= 1) {
        a0 += __shfl_xor(a0, m, 64); a1 += __shfl_xor(a1, m, 64);
        a2 += __shfl_xor(a2, m, 64); a3 += __shfl_xor(a3, m, 64);
        a4 += __shfl_xor(a4, m, 64); a5 += __shfl_xor(a5, m, 64);
        a6 += __shfl_xor(a6, m, 64); a7 += __shfl_xor(a7, m, 64);
        accE += __shfl_xor(accE, m, 64);
    }
    {
        float rE = frcp(accE);
        const float4* b1v = (const float4*)b1;
        float4 bA = b1v[oct * 2], bB = b1v[oct * 2 + 1];
        float v0 = a0 * rE + bA.x, v1 = a1 * rE + bA.y;
        float v2 = a2 * rE + bA.z, v3 = a3 * rE + bA.w;
        float v4 = a4 * rE + bB.x, v5 = a5 * rE + bB.y;
        float v6 = a6 * rE + bB.z, v7 = a7 * rE + bB.w;
        v0 = v0 > 0.f ? v0 : __expf(v0) - 1.f;
        v1 = v1 > 0.f ? v1 : __expf(v1) - 1.f;
        v2 = v2 > 0.f ? v2 : __expf(v2) - 1.f;
        v3 = v3 > 0.f ? v3 : __expf(v3) - 1.f;
        v4 = v4 > 0.f ? v4 : __expf(v4) - 1.f;
        v5 = v5 > 0.f ? v5 : __expf(v5) - 1.f;
        v6 = v6 > 0.f ? v6 : __expf(v6) - 1.f;
        v7 = v7 > 0.f ? v7 : __expf(v7) - 1.f;
        if (g == 0) {
            float4* hw = (float4*)&hrow[wv][oct * 8];
            hw[0] = make_float4(v0, v1, v2, v3);
            hw[1] = make_float4(v4, v5, v6, v7);
        }
    }
    __syncthreads();

    // fused layer-2 GEMM: lane (l, half); 64 fma over k-half, then combine
    {
        int l = t & 31, half = t >> 5;
        const float* hr = hrow[wv];
        int k0 = half * 64;
        float pacc = 0.f;
#pragma unroll 16
        for (int k = 0; k < 64; ++k)
            pacc += hr[k0 + k] * W2[(k0 + k) * 32 + l];
        pacc += __shfl_xor(pacc, 32, 64);     // both halves now hold h2[l]
        float hv2 = pacc;
        float ps = hv2 * att_s2[l];
        float pd = hv2 * att_d2[l];
        for (int m = 16; m >= 1; m >>= 1) {
            ps += __shfl_xor(ps, m, 64);
            pd += __shfl_xor(pd, m, 64);
        }
        if (t == 0) { as2[n] = ps; ad2[n] = pd; }
        float hvn = __shfl_down(hv2, 1, 64);
        if (t < 32 && (t & 1) == 0)
            h2u[n * 16 + (t >> 1)] = pack2(hv2, hvn);
    }
}

// ======================= layer 2 node aggregation =======================
// 4 nodes per 256-thread block (wave-per-node); packed slot reads;
// dual-stream gathers.
__global__ __launch_bounds__(256) void
node_agg2(const int* __restrict__ cnt, const int* __restrict__ slot,
          const float* __restrict__ as2, const float* __restrict__ ad2,
          const uint2* __restrict__ h2d, const float* __restrict__ b2,
          float* __restrict__ out) {
    int tb = threadIdx.x;
    int wv = tb >> 6, t = tb & 63;
    int n = blockIdx.x * 4 + wv;
    if (n >= N_NODES) return;
    int c = t & 7, g = t >> 3;      // column c: dims 4c..4c+3; 8 edge-groups
    int deg = min(cnt[n], SLOT_CAP);
    float ad = ad2[n];

    __shared__ float els[4][SLOT_CAP];
    __shared__ int  slds[4][SLOT_CAP];

    if (t < deg) {                   // deg <= 64: one shot, quad-coalesced
        int s = slot[slot_idx(t, n)];
        els[wv][t] = __expf(lrelu(as2[s] + ad));
        slds[wv][t] = s;
    }
    __syncthreads();

    float a0 = 0.f, a1 = 0.f, a2 = 0.f, a3 = 0.f;
    float accE = 0.f;
    for (int p = g; p < deg; p += 16) {
        float exA = els[wv][p];
        uint2 hvA = h2d[(size_t)slds[wv][p] * 8 + c];
        int pB = p + 8;
        float exB = 0.f;
        uint2 hvB = make_uint2(0u, 0u);
        if (pB < deg) {
            exB = els[wv][pB];
            hvB = h2d[(size_t)slds[wv][pB] * 8 + c];
        }
        accE += exA + exB;
        a0 += exA * bflo(hvA.x) + exB * bflo(hvB.x);
        a1 += exA * bfhi(hvA.x) + exB * bfhi(hvB.x);
        a2 += exA * bflo(hvA.y) + exB * bflo(hvB.y);
        a3 += exA * bfhi(hvA.y) + exB * bfhi(hvB.y);
    }
    for (int m = 8; m <= 32; m <<= 1) {
        a0 += __shfl_xor(a0, m, 64); a1 += __shfl_xor(a1, m, 64);
        a2 += __shfl_xor(a2, m, 64); a3 += __shfl_xor(a3, m, 64);
        accE += __shfl_xor(accE, m, 64);
    }
    if (t < 8) {
        float rE = frcp(accE);
        const float4* bb = (const float4*)(b2 + t * 4);
        float4 r = make_float4(a0 * rE + bb->x, a1 * rE + bb->y,
                               a2 * rE + bb->z, a3 * rE + bb->w);
        *(float4*)(out + n * 32 + t * 4) = r;
    }
}

extern "C" void kernel_launch(void* const* d_in, const int* in_sizes, int n_in,
                              void* d_out, int out_size, void* d_ws, size_t ws_size,
                              hipStream_t stream) {
    const float* x        = (const float*)d_in[0];
    const int*   ei       = (const int*)d_in[1];
    const float* W1       = (const float*)d_in[2];
    const float* att_src1 = (const float*)d_in[3];
    const float* att_dst1 = (const float*)d_in[4];
    const float* b1       = (const float*)d_in[5];
    const float* W2       = (const float*)d_in[6];
    const float* att_src2 = (const float*)d_in[7];
    const float* att_dst2 = (const float*)d_in[8];
    const float* b2       = (const float*)d_in[9];
    float* out = (float*)d_out;

    // workspace carve-up (~31 MB)
    float* p = (float*)d_ws;
    unsigned* h1u = (unsigned*)p; p += N_NODES * 64;   // bf16 h1, 12.8 MB
    unsigned* h2u = (unsigned*)p; p += N_NODES * 16;   // bf16 h2, 3.2 MB
    float* as1   = p; p += N_NODES * 4;
    float* ad1   = p; p += N_NODES * 4;
    float* as2   = p; p += N_NODES;
    float* ad2   = p; p += N_NODES;
    int* ip = (int*)p;
    int* cnt   = ip; ip += N_NODES;
    int* slot  = ip; ip += N_NODES * SLOT_CAP;         // 12.8 MB, packed quads

    hipMemsetAsync(cnt, 0, N_NODES * sizeof(int), stream);

    // ---- fused layer-1 GEMM + bucketing (independent, overlapped) ----
    gemm1_bucket<<<GEMM_BLOCKS + BUCKET_BLOCKS, 256, 0, stream>>>(
        x, W1, att_src1, att_dst1, h1u, as1, ad1, ei, cnt, slot);

    // ---- layer 1 aggregation (+ fused layer-2 GEMM), wave-per-node ----
    node_agg1<<<N_NODES / 2, 128, 0, stream>>>(cnt, slot, as1, ad1,
                                               (const uint4*)h1u, b1,
                                               W2, att_src2, att_dst2, h2u, as2, ad2);

    // ---- layer 2 aggregation (4 nodes/block) ----
    node_agg2<<<(N_NODES + 3) / 4, 256, 0, stream>>>(cnt, slot, as2, ad2,
                                                     (const uint2*)h2u, b2, out);
}